// Round 9
// baseline (56.858 us; speedup 1.0000x reference)
//
#include <hip/hip_runtime.h>

#define B 2
#define N 16384
#define NPOINT 4096
#define C 64
#define NSAMPLE 32

#define NCELL 1000        // 10x10x10 grid, cell size 0.1 == radius
#define OFF_STRIDE 1056   // offsets stride per batch (1001 used)
#define CAP 192           // per-query candidate capacity (mean ~69)

#define NTILE_BLOCKS (B * (N / 256))   // 128 transpose blocks (4 sub-tiles each)

// Threshold exactly as the JAX/numpy reference sees it:
// float32(double(0.1)*double(0.1)) = 0.009999999776482582f
__device__ __forceinline__ float r2_thresh() { return (float)(0.1 * 0.1); }

__device__ __forceinline__ int clamp09(int v) { return v < 0 ? 0 : (v > 9 ? 9 : v); }

__device__ __forceinline__ int cell_of(float x, float y, float z) {
    const int ix = clamp09((int)floorf(x * 10.0f));
    const int iy = clamp09((int)floorf(y * 10.0f));
    const int iz = clamp09((int)floorf(z * 10.0f));
    return (ix * 10 + iy) * 10 + iz;
}

// Exclusive scan of cnts[1024] -> cursors in cur[1024]; optionally write off[0..1000].
__device__ __forceinline__ void scan_and_cursor(int* cnts, int* cur, int t,
                                                int* off_global) {
    const int v = cnts[t];
    cur[t] = v;
    __syncthreads();
#pragma unroll
    for (int d = 1; d < 1024; d <<= 1) {
        const int add = (t >= d) ? cur[t - d] : 0;
        __syncthreads();
        cur[t] += add;
        __syncthreads();
    }
    const int excl = cur[t] - v;
    if (off_global && t <= NCELL) off_global[t] = excl;
    __syncthreads();
    cur[t] = excl;
    __syncthreads();
}

// ---------------- Kernel P: transpose (blocks 0..127) + grid build (blocks 128..129) ----------------
__global__ void __launch_bounds__(1024) prep_kernel(
    const float* __restrict__ feat,     // (B, C, N)
    const float* __restrict__ xyz,      // (B, N, 3)
    const float* __restrict__ new_xyz,  // (B, NPOINT, 3)
    float* __restrict__ ft,             // (B, N, C)
    float4* __restrict__ binned,        // (B, N) {x,y,z,idx}
    int* __restrict__ off,              // (B, OFF_STRIDE)
    int* __restrict__ qperm)            // (B, NPOINT)
{
    __shared__ float tile[64 * 65];
    __shared__ int cnts[1024];
    __shared__ int cur[1024];

    const int t = threadIdx.x;

    if (blockIdx.x < NTILE_BLOCKS) {
        // ---- transpose branch: 4 sub-tiles of 64n x 64c ----
        const int tb = blockIdx.x;
        const int b = tb / (N / 256);
        const int n0b = (tb % (N / 256)) * 256;
        const int l = t & 63;
        const int w = t >> 6;   // 0..15
        for (int si = 0; si < 4; ++si) {
            const int n0 = n0b + si * 64;
#pragma unroll
            for (int it = 0; it < 4; ++it) {
                const int c = it * 16 + w;
                tile[c * 65 + l] = feat[((size_t)b * C + c) * N + n0 + l];
            }
            __syncthreads();
#pragma unroll
            for (int it = 0; it < 4; ++it) {
                const int nn = it * 16 + w;
                ft[((size_t)b * N + n0 + nn) * C + l] = tile[l * 65 + nn];
            }
            __syncthreads();
        }
        return;
    }

    // ---- build branch: one block per batch, all counters in LDS ----
    const int b = blockIdx.x - NTILE_BLOCKS;

    // points: histogram
    cnts[t] = 0;
    __syncthreads();
    for (int i = t; i < N; i += 1024) {
        const float x = xyz[((size_t)b * N + i) * 3 + 0];
        const float y = xyz[((size_t)b * N + i) * 3 + 1];
        const float z = xyz[((size_t)b * N + i) * 3 + 2];
        atomicAdd(&cnts[cell_of(x, y, z)], 1);
    }
    __syncthreads();
    scan_and_cursor(cnts, cur, t, off + b * OFF_STRIDE);
    // points: scatter
    for (int i = t; i < N; i += 1024) {
        const float x = xyz[((size_t)b * N + i) * 3 + 0];
        const float y = xyz[((size_t)b * N + i) * 3 + 1];
        const float z = xyz[((size_t)b * N + i) * 3 + 2];
        const int pos = atomicAdd(&cur[cell_of(x, y, z)], 1);
        float4 v;
        v.x = x; v.y = y; v.z = z; v.w = __int_as_float(i);
        binned[(size_t)b * N + pos] = v;
    }
    __syncthreads();

    // queries: histogram
    cnts[t] = 0;
    __syncthreads();
    for (int i = t; i < NPOINT; i += 1024) {
        const float x = new_xyz[((size_t)b * NPOINT + i) * 3 + 0];
        const float y = new_xyz[((size_t)b * NPOINT + i) * 3 + 1];
        const float z = new_xyz[((size_t)b * NPOINT + i) * 3 + 2];
        atomicAdd(&cnts[cell_of(x, y, z)], 1);
    }
    __syncthreads();
    scan_and_cursor(cnts, cur, t, nullptr);
    // queries: scatter -> qperm (sorted position -> original query index)
    for (int i = t; i < NPOINT; i += 1024) {
        const float x = new_xyz[((size_t)b * NPOINT + i) * 3 + 0];
        const float y = new_xyz[((size_t)b * NPOINT + i) * 3 + 1];
        const float z = new_xyz[((size_t)b * NPOINT + i) * 3 + 2];
        const int pos = atomicAdd(&cur[cell_of(x, y, z)], 1);
        qperm[b * NPOINT + pos] = i;
    }
}

// ---------------- exact linear-scan fallback (in-wave); out may be LDS or global ----------------
__device__ void linear_ball_fallback(const float* __restrict__ xb,
                                     float cx, float cy, float cz,
                                     int lane, unsigned long long lanemask_lt,
                                     int* out) {
    const float r2 = r2_thresh();
    int cnt = 0, first_idx = 0;
    for (int base = 0; base < N; base += 64) {
        const int i = base + lane;
        const float x = xb[i * 3 + 0];
        const float y = xb[i * 3 + 1];
        const float z = xb[i * 3 + 2];
        float d2;
        {
#pragma clang fp contract(off)
            float dx = x - cx;
            float dy = y - cy;
            float dz = z - cz;
            d2 = dx * dx + dy * dy + dz * dz;
        }
        const bool in = d2 < r2;
        const unsigned long long m = __ballot(in);
        if (in) {
            const int pos = cnt + __popcll(m & lanemask_lt);
            if (pos < NSAMPLE) out[pos] = i;
        }
        if (cnt == 0 && m != 0ull) first_idx = base + __builtin_ctzll(m);
        cnt += __popcll(m);
        if (cnt >= NSAMPLE) break;
    }
    if (cnt < NSAMPLE) {
        if (cnt == 0) first_idx = 0;
        for (int pos = cnt + lane; pos < NSAMPLE; pos += 64) out[pos] = first_idx;
    }
}

// ---------------- Kernel F: fused ball query + grouping ----------------
// 256 threads = 4 waves = 4 consecutive sorted queries. Ball query via grid
// into LDS sidx; then block-cooperative gather of ft rows and coalesced
// channel-plane stores. idx never hits global memory.
__global__ void __launch_bounds__(256) fused_kernel(
    const float4* __restrict__ binned,   // (B, N)
    const int* __restrict__ off,         // (B, OFF_STRIDE)
    const float* __restrict__ new_xyz,   // (B, NPOINT, 3)
    const float* __restrict__ xyz,       // (B, N, 3)
    const float* __restrict__ ft,        // (B, N, C)
    const int* __restrict__ qperm,       // (B, NPOINT)
    float* __restrict__ out)             // (B, 3+C, NPOINT, NSAMPLE)
{
    __shared__ int cand_s[4][CAP];
    __shared__ int sidx[4 * NSAMPLE];   // 128 selected ids
    __shared__ int sj[4];               // original query index per wave
    __shared__ float sf[128 * 65];      // [pair][channel], pad 65

    const int t = threadIdx.x;
    const int lane = t & 63;
    const int w = t >> 6;   // wave = local query

    const int nwg = B * NPOINT / 4;                 // 2048, % 8 == 0
    const int g = blockIdx.x;
    const int swz = (g & 7) * (nwg / 8) + (g >> 3); // bijective XCD swizzle
    const int b = swz / (NPOINT / 4);
    const int p4 = swz % (NPOINT / 4);

    const int j = qperm[b * NPOINT + p4 * 4 + w];   // original query (broadcast)
    if (lane == 0) sj[w] = j;

    const float cx = new_xyz[((size_t)b * NPOINT + j) * 3 + 0];
    const float cy = new_xyz[((size_t)b * NPOINT + j) * 3 + 1];
    const float cz = new_xyz[((size_t)b * NPOINT + j) * 3 + 2];

    int* cand = cand_s[w];
    int* sout = sidx + w * NSAMPLE;
    const float4* __restrict__ bb = binned + (size_t)b * N;
    const int* __restrict__ ob = off + b * OFF_STRIDE;

    const float r2 = r2_thresh();
    const unsigned long long lanemask_lt = (lane == 63) ? 0x7FFFFFFFFFFFFFFFull
                                                        : ((1ull << lane) - 1ull);

    // Window from coordinates +-0.1001 (covers FP boundary rounding; <=3 cells/axis)
    const int lox = max(0, (int)floorf((cx - 0.1001f) * 10.0f));
    const int hix = min(9, (int)floorf((cx + 0.1001f) * 10.0f));
    const int loy = max(0, (int)floorf((cy - 0.1001f) * 10.0f));
    const int hiy = min(9, (int)floorf((cy + 0.1001f) * 10.0f));
    const int loz = max(0, (int)floorf((cz - 0.1001f) * 10.0f));
    const int hiz = min(9, (int)floorf((cz + 0.1001f) * 10.0f));

    int K = 0;
    for (int ix = lox; ix <= hix; ++ix) {
        for (int iy = loy; iy <= hiy; ++iy) {
            const int rowc = (ix * 10 + iy) * 10;
            const int s0 = ob[rowc + loz];
            const int s1 = ob[rowc + hiz + 1];  // z cells contiguous -> one segment
            for (int curp = s0; curp < s1; curp += 64) {
                const int i = curp + lane;
                const bool valid = (i < s1);
                float4 pv;
                if (valid) pv = bb[i];
                else { pv.x = 1e9f; pv.y = 1e9f; pv.z = 1e9f; pv.w = 0.0f; }
                float d2;
                {
#pragma clang fp contract(off)
                    float dx = pv.x - cx;
                    float dy = pv.y - cy;
                    float dz = pv.z - cz;
                    d2 = dx * dx + dy * dy + dz * dz;
                }
                const bool in = valid && (d2 < r2);
                const unsigned long long m = __ballot(in);
                if (in) {
                    const int pos = K + __popcll(m & lanemask_lt);
                    if (pos < CAP) cand[pos] = __float_as_int(pv.w);
                }
                K += __popcll(m);
            }
        }
    }

    if (K > CAP) {
        // pathological density: exact linear rescan into LDS (wave-uniform)
        linear_ball_fallback(xyz + (size_t)b * N * 3, cx, cy, cz, lane, lanemask_lt, sout);
    } else {
        // Rank selection: rank(e) = #{candidates with smaller index}; ids unique.
        const int e0 = (lane < K) ? cand[lane] : 0x7FFFFFFF;
        const int e1 = (64 + lane < K) ? cand[64 + lane] : 0x7FFFFFFF;
        const int e2 = (128 + lane < K) ? cand[128 + lane] : 0x7FFFFFFF;
        int r0 = 0, r1 = 0, r2i = 0;
        if (K <= 64) {
            for (int k = 0; k < K; ++k) { const int v = cand[k]; r0 += (v < e0); }
        } else if (K <= 128) {
            for (int k = 0; k < K; ++k) { const int v = cand[k]; r0 += (v < e0); r1 += (v < e1); }
        } else {
            for (int k = 0; k < K; ++k) {
                const int v = cand[k];
                r0 += (v < e0); r1 += (v < e1); r2i += (v < e2);
            }
        }
        if (lane < K && r0 < NSAMPLE) sout[r0] = e0;
        if (64 + lane < K && r1 < NSAMPLE) sout[r1] = e1;
        if (128 + lane < K && r2i < NSAMPLE) sout[r2i] = e2;

        if (K < NSAMPLE) {
            int mn = min(e0, min(e1, e2));
#pragma unroll
            for (int d = 32; d; d >>= 1) mn = min(mn, __shfl_xor(mn, d));
            const int fill = (K > 0) ? mn : 0;
            for (int pos = K + lane; pos < NSAMPLE; pos += 64) sout[pos] = fill;
        }
    }
    __syncthreads();

    const size_t plane = (size_t)NPOINT * NSAMPLE;
    const size_t bbase = (size_t)b * (3 + C) * plane;

    // xyz part: threads 0..127 -> one pair each
    if (t < 128) {
        const int id = sidx[t];
        const int jq = sj[t >> 5];
        const int s = t & 31;
        const size_t cb = ((size_t)b * NPOINT + jq) * 3;
        const size_t pb = ((size_t)b * N + id) * 3;
        const size_t obx = bbase + (size_t)jq * NSAMPLE + s;
        {
#pragma clang fp contract(off)
            out[obx + 0 * plane] = xyz[pb + 0] - new_xyz[cb + 0];
            out[obx + 1 * plane] = xyz[pb + 1] - new_xyz[cb + 1];
            out[obx + 2 * plane] = xyz[pb + 2] - new_xyz[cb + 2];
        }
    }

    // gather: 128 pairs, 16 lanes per pair, one float4 each, 8 iterations
    {
        const int lane16 = t & 15;
        const int pg = t >> 4;  // 0..15
#pragma unroll
        for (int it = 0; it < 8; ++it) {
            const int pp = it * 16 + pg;
            const int id = sidx[pp];
            const float4 v = *(const float4*)(ft + ((size_t)b * N + id) * C + lane16 * 4);
            float* dst = sf + pp * 65 + lane16 * 4;
            dst[0] = v.x; dst[1] = v.y; dst[2] = v.z; dst[3] = v.w;
        }
    }
    __syncthreads();

    // store: wave w owns channels c = it*4 + w; two 64-pair halves per channel
#pragma unroll
    for (int it = 0; it < 16; ++it) {
        const int c = it * 4 + w;
#pragma unroll
        for (int half = 0; half < 2; ++half) {
            const int pr = half * 64 + lane;
            const int jq = sj[pr >> 5];
            out[bbase + (size_t)(3 + c) * plane + (size_t)jq * NSAMPLE + (pr & 31)] =
                sf[pr * 65 + c];
        }
    }
}

// ---------------- ws-too-small fallbacks (linear ball + direct group) ----------------
__global__ void __launch_bounds__(256) ball_query_kernel(
    const float* __restrict__ xyz, const float* __restrict__ new_xyz,
    int* __restrict__ idx_out)
{
    const int wave = (blockIdx.x * blockDim.x + threadIdx.x) >> 6;
    const int lane = threadIdx.x & 63;
    if (wave >= B * NPOINT) return;
    const int b = wave / NPOINT;
    const float cx = new_xyz[(size_t)wave * 3 + 0];
    const float cy = new_xyz[(size_t)wave * 3 + 1];
    const float cz = new_xyz[(size_t)wave * 3 + 2];
    const unsigned long long lanemask_lt = (lane == 63) ? 0x7FFFFFFFFFFFFFFFull
                                                        : ((1ull << lane) - 1ull);
    linear_ball_fallback(xyz + (size_t)b * N * 3, cx, cy, cz, lane, lanemask_lt,
                         idx_out + (size_t)wave * NSAMPLE);
}

__global__ void __launch_bounds__(256) group_kernel(
    const float* __restrict__ xyz, const float* __restrict__ new_xyz,
    const float* __restrict__ feat, const int* __restrict__ idx_arr,
    float* __restrict__ out) {
    const int t = threadIdx.x;
    const int s = t & 31;
    const int jl = t >> 5;
    const int j = blockIdx.x * 8 + jl;
    const int b = blockIdx.y;

    const int id = idx_arr[((size_t)b * NPOINT + j) * NSAMPLE + s];

    const float px = xyz[((size_t)b * N + id) * 3 + 0] - new_xyz[((size_t)b * NPOINT + j) * 3 + 0];
    const float py = xyz[((size_t)b * N + id) * 3 + 1] - new_xyz[((size_t)b * NPOINT + j) * 3 + 1];
    const float pz = xyz[((size_t)b * N + id) * 3 + 2] - new_xyz[((size_t)b * NPOINT + j) * 3 + 2];

    const size_t plane = (size_t)NPOINT * NSAMPLE;
    const size_t obase = (size_t)b * (3 + C) * plane + (size_t)j * NSAMPLE + s;

    out[obase + 0 * plane] = px;
    out[obase + 1 * plane] = py;
    out[obase + 2 * plane] = pz;

    const float* __restrict__ fb = feat + (size_t)b * C * N;
#pragma unroll 8
    for (int c = 0; c < C; ++c) {
        out[obase + (size_t)(3 + c) * plane] = fb[(size_t)c * N + id];
    }
}

extern "C" void kernel_launch(void* const* d_in, const int* in_sizes, int n_in,
                              void* d_out, int out_size, void* d_ws, size_t ws_size,
                              hipStream_t stream) {
    const float* xyz     = (const float*)d_in[0];  // (B, N, 3)
    const float* new_xyz = (const float*)d_in[1];  // (B, NPOINT, 3)
    const float* feat    = (const float*)d_in[2];  // (B, C, N)
    float* out = (float*)d_out;

    // Workspace layout (contiguous)
    const size_t idx_bytes    = (size_t)B * NPOINT * NSAMPLE * sizeof(int);  // fallback only
    const size_t ft_bytes     = (size_t)B * N * C * sizeof(float);           // 8,388,608
    const size_t binned_bytes = (size_t)B * N * sizeof(float4);              //   524,288
    const size_t off_bytes    = (size_t)B * OFF_STRIDE * sizeof(int);        //     8,448
    const size_t qperm_bytes  = (size_t)B * NPOINT * sizeof(int);            //    32,768

    char* ws = (char*)d_ws;
    size_t o = 0;
    int*    idx_ws = (int*)(ws + o);    o += idx_bytes;
    float*  ft     = (float*)(ws + o);  o += ft_bytes;
    float4* binned = (float4*)(ws + o); o += binned_bytes;
    int*    off    = (int*)(ws + o);    o += off_bytes;
    int*    qperm  = (int*)(ws + o);    o += qperm_bytes;

    const bool use_grid = (ws_size >= o);

    if (use_grid) {
        prep_kernel<<<NTILE_BLOCKS + B, 1024, 0, stream>>>(
            feat, xyz, new_xyz, ft, binned, off, qperm);
        fused_kernel<<<B * NPOINT / 4, 256, 0, stream>>>(
            binned, off, new_xyz, xyz, ft, qperm, out);
    } else {
        ball_query_kernel<<<(B * NPOINT) / 4, 256, 0, stream>>>(xyz, new_xyz, idx_ws);
        dim3 grid2(NPOINT / 8, B);
        group_kernel<<<grid2, 256, 0, stream>>>(xyz, new_xyz, feat, idx_ws, out);
    }
}